// Round 9
// baseline (177.533 us; speedup 1.0000x reference)
//
#include <hip/hip_runtime.h>
#include <hip/hip_bf16.h>
#include <math.h>

// Problem constants (from reference): B=4, T=8192, D=512, S=16
#define B_ 4
#define T_ 8192
#define D_ 512
#define S_ 16

// tokens per block for attn_ts_k (64 -> 512 blocks, 4 waves x 16 tokens)
#define CHUNK 64

// ---------------------------------------------------------------------------
// JOURNAL (measured, gfx950):
// R0: attn(VALU,124regs)=57.7us, total 177.5.
// R1: launch_bounds cap below true need SPILLS (hbm 82->470MB). Never.
// R2: attn CHUNK=32 VALU = 50.4us. out float4 ssf crossed 64-reg step: 195.
// R3: lane-per-(token,splat): 16 lanes share x addr -> VMEM-issue-bound, 80us.
// R4: out_k LDS-staged+(256,4): rest ~12us worse than R0. attn 52. total 183.
// R5: phase A -> MFMA (verified): attn ~45us, VGPR 68, occ 17%. total 179.5.
// R6: K-split occupancy fix: occ 30% -- attn 50us WORSE. Occupancy not binding.
// R7: infra failure. R8 = R7 design, passed: attn ~49us, VALUBusy 15->11%,
//     total 176.4 BEST. Duration flat despite less VALU work =>
//     LATENCY-QUEUE-BOUND: FETCH 62MB/49us = 1.6 TB/s with VALU+MFMA idle;
//     K-loop holds only ~2 in-flight loads/lane (VGPR 68 = no hoisting).
// R9: depth-4 rotating register prefetch in phase A K-loop (8 KB in
//     flight/wave vs 2 KB). VGPR ~100 (stays in 65..128 band -> occupancy
//     unchanged). Everything else byte-identical to R8.
// OCCUPANCY LAW: VGPR<=64 -> 4 w/SIMD; 65..128 -> 2 w/SIMD; grid caps blocks.
// ---------------------------------------------------------------------------

typedef __attribute__((ext_vector_type(8))) short bf16x8;   // 8 bf16 (4 VGPRs)
typedef __attribute__((ext_vector_type(4))) float f32x4;    // mfma C/D

__device__ __forceinline__ float dot4(float4 a, float4 b) {
  return a.x * b.x + a.y * b.y + a.z * b.z + a.w * b.w;
}

// pack 8 fp32 -> 8 bf16 (RNE), as the short8 the mfma builtin takes
__device__ __forceinline__ bf16x8 pack8(float4 a, float4 b) {
  union { __hip_bfloat162 h[4]; bf16x8 v; } u;
  u.h[0] = __float22bfloat162_rn(make_float2(a.x, a.y));
  u.h[1] = __float22bfloat162_rn(make_float2(a.z, a.w));
  u.h[2] = __float22bfloat162_rn(make_float2(b.x, b.y));
  u.h[3] = __float22bfloat162_rn(make_float2(b.z, b.w));
  return u.v;
}

// ---------------------------------------------------------------------------
// Fused attn + token->splat aggregation. 512 blocks x 256 threads (4 waves).
//
// Setup: block cooperatively packs centers into LDS B-fragments cf_s[st][lane]
// (16 KB); c2[n] computed deterministically by wave 0 (R5-verified shuffles).
//
// Phase A (MFMA, depth-4 pipelined): wave w owns tokens tw..tw+15. K-loop
// (16 steps): rotating 4-deep register buffer keeps 8 x-loads (8 KB/wave)
// in flight; each step: consume buffer, re-issue for st+4, ds_read cf,
// pack, one mfma_f32_16x16x32_bf16. D-layout: lane = splat n=lane&15,
// token rows (lane>>4)*4+r [m89/R5-verified]. Uniform-scale ballot drops
// the x2 term (softmax-invariant shift; R5-verified full path fallback).
//
// Phase B: EXACT R0/R5/R8 (proven): thread owns cols d,d+256; streams
// chunk's x rows (L2-hot) against LDS-broadcast attn; atomicAdds into ts.
// ---------------------------------------------------------------------------
__global__ __launch_bounds__(256, 2) void attn_ts_k(const float* __restrict__ x,
                                                    const float* __restrict__ centers,
                                                    const float* __restrict__ log_scales,
                                                    float* __restrict__ attn,
                                                    float* __restrict__ ts) {
  __shared__ __align__(16) float a_s[CHUNK][S_];   // 4 KB
  __shared__ __align__(16) bf16x8 cf_s[16][64];    // 16 KB packed B-fragments
  __shared__ float c2_s[S_];
  const int tid = threadIdx.x;
  const int lane = tid & 63;
  const int w = tid >> 6;   // wave 0..3
  const int g = lane >> 4;  // k-group 0..3
  const int n = lane & 15;  // A-row token idx == B-col splat idx
  const int b = blockIdx.x >> 7;              // 128 chunks per batch
  const int t0 = (blockIdx.x & 127) * CHUNK;  // 64 tokens per block
  const int tw = t0 + (w << 4);               // this wave's 16 tokens

  // ---- cooperative center staging (once per block) ----
#pragma unroll
  for (int i = 0; i < 4; ++i) {
    int e = i * 256 + tid;         // (st, lane-slot) entry 0..1023
    int st = e >> 6;
    int ln = e & 63;
    int nn = ln & 15, gg = ln >> 4;
    const float* src = centers + nn * D_ + st * 32 + (gg << 3);
    float4 c0 = *(const float4*)(src);
    float4 c1 = *(const float4*)(src + 4);
    cf_s[st][ln] = pack8(c0, c1);
  }
  // deterministic c2 on wave 0 (R5-verified xor-16/32 completion)
  if (w == 0) {
    const float* crow = centers + n * D_ + (g << 7);
    float c2p = 0.f;
#pragma unroll
    for (int k = 0; k < 32; ++k) {
      float4 cv = *(const float4*)(crow + (k << 2));
      c2p += dot4(cv, cv);
    }
    c2p += __shfl_xor(c2p, 16, 64);
    c2p += __shfl_xor(c2p, 32, 64);
    if (lane < S_) c2_s[lane] = c2p;
  }
  __syncthreads();

  // ---- Phase A ----
  {
    const float sc = fminf(fmaxf(__expf(log_scales[n]), 0.1f), 2.0f);
    const float inv2 = 0.5f / (sc * sc);
    // uniform-scale fast path: x2 is a per-token constant in the softmax
    const bool uni =
        (__ballot(sc == __shfl(sc, 0, 64)) == 0xFFFFFFFFFFFFFFFFull);

    const float* xrow = x + ((size_t)b * T_ + tw + n) * D_ + (g << 3);
    f32x4 acc = {0.f, 0.f, 0.f, 0.f};
    float x2p = 0.f;

    // depth-4 rotating prefetch buffer (fully unrolled -> register-resident)
    float4 pb0[4], pb1[4];
#pragma unroll
    for (int i = 0; i < 4; ++i) {
      pb0[i] = *(const float4*)(xrow + i * 32);
      pb1[i] = *(const float4*)(xrow + i * 32 + 4);
    }

    if (uni) {
#pragma unroll
      for (int st = 0; st < 16; ++st) {
        float4 x0 = pb0[st & 3], x1 = pb1[st & 3];
        if (st < 12) {  // re-issue this slot for st+4 (8 KB/wave in flight)
          pb0[st & 3] = *(const float4*)(xrow + (st + 4) * 32);
          pb1[st & 3] = *(const float4*)(xrow + (st + 4) * 32 + 4);
        }
        acc = __builtin_amdgcn_mfma_f32_16x16x32_bf16(pack8(x0, x1),
                                                      cf_s[st][lane], acc,
                                                      0, 0, 0);
      }
    } else {
#pragma unroll
      for (int st = 0; st < 16; ++st) {
        float4 x0 = pb0[st & 3], x1 = pb1[st & 3];
        if (st < 12) {
          pb0[st & 3] = *(const float4*)(xrow + (st + 4) * 32);
          pb1[st & 3] = *(const float4*)(xrow + (st + 4) * 32 + 4);
        }
        x2p += dot4(x0, x0) + dot4(x1, x1);
        acc = __builtin_amdgcn_mfma_f32_16x16x32_bf16(pack8(x0, x1),
                                                      cf_s[st][lane], acc,
                                                      0, 0, 0);
      }
      x2p += __shfl_xor(x2p, 16, 64);
      x2p += __shfl_xor(x2p, 32, 64);  // x2 for token tw+n (all lanes)
    }

    const float c2 = c2_s[n];

    // logits: lane holds splat n, token rows (g*4+r)  [R5-verified layout]
    float lg[4];
#pragma unroll
    for (int r = 0; r < 4; ++r) {
      float t = 2.f * acc[r] - c2;
      if (!uni) t -= __shfl(x2p, (lane & 48) | ((g << 2) + r), 64);
      lg[r] = t * inv2;
    }

    // softmax across splats (16-lane groups), 4 tokens per lane (R5-verified)
    float mx[4] = {lg[0], lg[1], lg[2], lg[3]};
#pragma unroll
    for (int dlt = 1; dlt < 16; dlt <<= 1)
#pragma unroll
      for (int r = 0; r < 4; ++r) mx[r] = fmaxf(mx[r], __shfl_xor(mx[r], dlt, 64));
    float ev[4], sm[4];
#pragma unroll
    for (int r = 0; r < 4; ++r) { ev[r] = __expf(lg[r] - mx[r]); sm[r] = ev[r]; }
#pragma unroll
    for (int dlt = 1; dlt < 16; dlt <<= 1)
#pragma unroll
      for (int r = 0; r < 4; ++r) sm[r] += __shfl_xor(sm[r], dlt, 64);

    float* ar = attn + ((size_t)b * T_ + tw) * S_;
#pragma unroll
    for (int r = 0; r < 4; ++r) {
      float av = ev[r] / sm[r];
      int trow = (g << 2) + r;
      ar[trow * S_ + n] = av;
      a_s[(w << 4) + trow][n] = av;
    }
  }

  __syncthreads();

  // ---- Phase B (exact R0/R5/R8, proven) ----
  {
    const int d = tid;  // owns cols d and d+256
    float2 acc[S_];
#pragma unroll
    for (int si = 0; si < S_; ++si) acc[si] = make_float2(0.f, 0.f);

    const float* xb = x + ((size_t)b * T_ + t0) * D_;

#pragma unroll 8
    for (int t = 0; t < CHUNK; ++t) {
      float xv0 = xb[(size_t)t * D_ + d];
      float xv1 = xb[(size_t)t * D_ + d + 256];
      const float4* ap = (const float4*)a_s[t];  // LDS broadcast
      float4 q0 = ap[0], q1 = ap[1], q2 = ap[2], q3 = ap[3];
      float av[S_] = {q0.x, q0.y, q0.z, q0.w, q1.x, q1.y, q1.z, q1.w,
                      q2.x, q2.y, q2.z, q2.w, q3.x, q3.y, q3.z, q3.w};
#pragma unroll
      for (int si = 0; si < S_; ++si) {
        acc[si].x += av[si] * xv0;
        acc[si].y += av[si] * xv1;
      }
    }

    float* tb = ts + (size_t)b * S_ * D_;
#pragma unroll
    for (int si = 0; si < S_; ++si) {
      atomicAdd(tb + si * D_ + d, acc[si].x);
      atomicAdd(tb + si * D_ + d + 256, acc[si].y);
    }
  }
}

// ---------------------------------------------------------------------------
// Kernel 2 (x2): out[r,e] = sum_k in[r,k] * W[e,k]   (r = 0..63 = b*S+s)
// Split-K=4 reduced in LDS (deterministic). 512 blocks x 256 threads.
// ---------------------------------------------------------------------------
__global__ __launch_bounds__(256) void proj_k(const float* __restrict__ in,
                                              const float* __restrict__ W,
                                              float* __restrict__ out) {
  __shared__ float red[4][64];
  const int r = blockIdx.x >> 3;
  const int eb = blockIdx.x & 7;
  const int el = threadIdx.x & 63;
  const int kc = threadIdx.x >> 6;
  const int e = (eb << 6) + el;

  const float4* w4 = (const float4*)(W + (size_t)e * D_ + kc * 128);
  const float4* i4 = (const float4*)(in + (size_t)r * D_ + kc * 128);
  float acc = 0.f;
#pragma unroll
  for (int k = 0; k < 32; ++k) acc += dot4(w4[k], i4[k]);

  red[kc][el] = acc;
  __syncthreads();
  if (kc == 0)
    out[(size_t)r * D_ + e] = red[0][el] + red[1][el] + red[2][el] + red[3][el];
}

// ---------------------------------------------------------------------------
// Kernel 3: out[b,t,e] = sum_s attn[b,t,s] * ss_o[b,s,e]
// EXACT R0 form (512 blocks, 64 tokens, float2 ssf): proven best inside the
// 176-177 totals. (R2 float4 ssf: reg-step. R4 LDS+cap: worse.)
// ---------------------------------------------------------------------------
#define K4_TOK 64
__global__ __launch_bounds__(256) void out_k(const float* __restrict__ attn,
                                             const float* __restrict__ ss_o,
                                             float* __restrict__ out) {
  const int chunks = T_ / K4_TOK;  // 128
  const int b = blockIdx.x / chunks;
  const int t0 = (blockIdx.x % chunks) * K4_TOK;
  const int w = threadIdx.x >> 6;
  const int lane = threadIdx.x & 63;
  const int e0 = (w << 7) + (lane << 1);

  float2 ssf[S_];
  const float* sb = ss_o + (size_t)b * S_ * D_;
#pragma unroll
  for (int s = 0; s < S_; ++s) ssf[s] = *(const float2*)(sb + s * D_ + e0);

  const float4* ab = (const float4*)(attn + ((size_t)b * T_ + t0) * S_);
  float* ob = out + ((size_t)b * T_ + t0) * D_ + e0;

#pragma unroll 4
  for (int t = 0; t < K4_TOK; ++t) {
    float4 a0 = ab[t * 4 + 0], a1 = ab[t * 4 + 1];
    float4 a2 = ab[t * 4 + 2], a3 = ab[t * 4 + 3];
    float av[S_] = {a0.x, a0.y, a0.z, a0.w, a1.x, a1.y, a1.z, a1.w,
                    a2.x, a2.y, a2.z, a2.w, a3.x, a3.y, a3.z, a3.w};
    float2 acc = make_float2(0.f, 0.f);
#pragma unroll
    for (int s = 0; s < S_; ++s) {
      acc.x += av[s] * ssf[s].x;
      acc.y += av[s] * ssf[s].y;
    }
    *(float2*)(ob + (size_t)t * D_) = acc;
  }
}

// ---------------------------------------------------------------------------
extern "C" void kernel_launch(void* const* d_in, const int* in_sizes, int n_in,
                              void* d_out, int out_size, void* d_ws, size_t ws_size,
                              hipStream_t stream) {
  const float* x          = (const float*)d_in[0];  // [B,T,D]
  const float* centers    = (const float*)d_in[1];  // [S,D]
  const float* log_scales = (const float*)d_in[2];  // [S]
  const float* Wv         = (const float*)d_in[3];  // [D,D]
  const float* Wo         = (const float*)d_in[4];  // [D,D]
  float* out = (float*)d_out;                       // [B,T,D]

  // workspace layout (floats): attn | ts | tmp | ss_o
  float* attn = (float*)d_ws;                        // B*T*S   = 2 MB
  float* ts   = attn + (size_t)B_ * T_ * S_;         // B*S*D   = 128 KB
  float* tmp  = ts + (size_t)B_ * S_ * D_;           // B*S*D   = 128 KB
  float* ss_o = tmp + (size_t)B_ * S_ * D_;          // B*S*D   = 128 KB

  // zero only the atomic target (tiny, L2-resident fill)
  hipMemsetAsync(ts, 0, (size_t)B_ * S_ * D_ * sizeof(float), stream);

  attn_ts_k<<<B_ * (T_ / CHUNK), 256, 0, stream>>>(x, centers, log_scales, attn, ts);
  proj_k<<<512, 256, 0, stream>>>(ts, Wv, tmp);    // tmp = ts @ Wv^T
  proj_k<<<512, 256, 0, stream>>>(tmp, Wo, ss_o);  // ss_o = tmp @ Wo^T
  out_k<<<B_ * (T_ / K4_TOK), 256, 0, stream>>>(attn, ss_o, out);
}

// Round 10
// 170.235 us; speedup vs baseline: 1.0429x; 1.0429x over previous
//
#include <hip/hip_runtime.h>
#include <hip/hip_bf16.h>
#include <math.h>

// Problem constants (from reference): B=4, T=8192, D=512, S=16
#define B_ 4
#define T_ 8192
#define D_ 512
#define S_ 16

// tokens per block for attn_ts_k (64 -> 512 blocks, 4 waves x 16 tokens)
#define CHUNK 64

// ---------------------------------------------------------------------------
// JOURNAL (measured, gfx950):
// R0: attn(VALU,124regs)=57.7us, total 177.5.
// R1: launch_bounds cap below true need SPILLS (hbm 82->470MB). Never.
//     R1 fit: attn 141 + out 193 = 334 of 387 -> non-kernel overhead ~50us.
// R2: attn CHUNK=32 VALU = 50.4us. out float4 ssf crossed 64-reg step: 195.
// R3: lane-per-(token,splat): VMEM-issue-bound, 80us.
// R4: out_k LDS-staged+(256,4): worse. attn 52. total 183.
// R5: phase A -> MFMA (verified layouts): attn ~45, total 179.5.
// R6: K-split occ 30%: attn 50 WORSE. Occupancy not binding.
// R8: center-frags in LDS + uniform-scale x2 drop: attn 49, VALUBusy 11%,
//     total 176.4 BEST. -> latency-queue-bound.
// R9: depth-4 reg prefetch: VGPR STAYED 68 -> compiler sank the loads,
//     pipeline defeated at source level. Warm attn 43, total flat.
//     Profile exposed: harness poison-fills 2x256MB/43us (not ours);
//     out_k never in top-5 but carries the same dependent-chain disease.
// R10: out_k -> MFMA (K=16 GEMM via verified 16x16x32 intrinsic, k>=16
//     zeroed). ss_o staged to LDS bf16 frags; kernel becomes a store
//     stream. attn/proj byte-identical to R9 (isolate delta).
// OCCUPANCY LAW: VGPR<=64 -> 4 w/SIMD; 65..128 -> 2 w/SIMD; grid caps blocks.
// ---------------------------------------------------------------------------

typedef __attribute__((ext_vector_type(8))) short bf16x8;   // 8 bf16 (4 VGPRs)
typedef __attribute__((ext_vector_type(4))) float f32x4;    // mfma C/D

__device__ __forceinline__ float dot4(float4 a, float4 b) {
  return a.x * b.x + a.y * b.y + a.z * b.z + a.w * b.w;
}

// pack 8 fp32 -> 8 bf16 (RNE), as the short8 the mfma builtin takes
__device__ __forceinline__ bf16x8 pack8(float4 a, float4 b) {
  union { __hip_bfloat162 h[4]; bf16x8 v; } u;
  u.h[0] = __float22bfloat162_rn(make_float2(a.x, a.y));
  u.h[1] = __float22bfloat162_rn(make_float2(a.z, a.w));
  u.h[2] = __float22bfloat162_rn(make_float2(b.x, b.y));
  u.h[3] = __float22bfloat162_rn(make_float2(b.z, b.w));
  return u.v;
}

// ---------------------------------------------------------------------------
// Fused attn + token->splat aggregation — EXACT R9 (best attn measured).
// ---------------------------------------------------------------------------
__global__ __launch_bounds__(256, 2) void attn_ts_k(const float* __restrict__ x,
                                                    const float* __restrict__ centers,
                                                    const float* __restrict__ log_scales,
                                                    float* __restrict__ attn,
                                                    float* __restrict__ ts) {
  __shared__ __align__(16) float a_s[CHUNK][S_];   // 4 KB
  __shared__ __align__(16) bf16x8 cf_s[16][64];    // 16 KB packed B-fragments
  __shared__ float c2_s[S_];
  const int tid = threadIdx.x;
  const int lane = tid & 63;
  const int w = tid >> 6;   // wave 0..3
  const int g = lane >> 4;  // k-group 0..3
  const int n = lane & 15;  // A-row token idx == B-col splat idx
  const int b = blockIdx.x >> 7;              // 128 chunks per batch
  const int t0 = (blockIdx.x & 127) * CHUNK;  // 64 tokens per block
  const int tw = t0 + (w << 4);               // this wave's 16 tokens

  // ---- cooperative center staging (once per block) ----
#pragma unroll
  for (int i = 0; i < 4; ++i) {
    int e = i * 256 + tid;         // (st, lane-slot) entry 0..1023
    int st = e >> 6;
    int ln = e & 63;
    int nn = ln & 15, gg = ln >> 4;
    const float* src = centers + nn * D_ + st * 32 + (gg << 3);
    float4 c0 = *(const float4*)(src);
    float4 c1 = *(const float4*)(src + 4);
    cf_s[st][ln] = pack8(c0, c1);
  }
  // deterministic c2 on wave 0 (R5-verified xor-16/32 completion)
  if (w == 0) {
    const float* crow = centers + n * D_ + (g << 7);
    float c2p = 0.f;
#pragma unroll
    for (int k = 0; k < 32; ++k) {
      float4 cv = *(const float4*)(crow + (k << 2));
      c2p += dot4(cv, cv);
    }
    c2p += __shfl_xor(c2p, 16, 64);
    c2p += __shfl_xor(c2p, 32, 64);
    if (lane < S_) c2_s[lane] = c2p;
  }
  __syncthreads();

  // ---- Phase A ----
  {
    const float sc = fminf(fmaxf(__expf(log_scales[n]), 0.1f), 2.0f);
    const float inv2 = 0.5f / (sc * sc);
    // uniform-scale fast path: x2 is a per-token constant in the softmax
    const bool uni =
        (__ballot(sc == __shfl(sc, 0, 64)) == 0xFFFFFFFFFFFFFFFFull);

    const float* xrow = x + ((size_t)b * T_ + tw + n) * D_ + (g << 3);
    f32x4 acc = {0.f, 0.f, 0.f, 0.f};
    float x2p = 0.f;

    // depth-4 rotating prefetch buffer (fully unrolled -> register-resident)
    float4 pb0[4], pb1[4];
#pragma unroll
    for (int i = 0; i < 4; ++i) {
      pb0[i] = *(const float4*)(xrow + i * 32);
      pb1[i] = *(const float4*)(xrow + i * 32 + 4);
    }

    if (uni) {
#pragma unroll
      for (int st = 0; st < 16; ++st) {
        float4 x0 = pb0[st & 3], x1 = pb1[st & 3];
        if (st < 12) {  // re-issue this slot for st+4
          pb0[st & 3] = *(const float4*)(xrow + (st + 4) * 32);
          pb1[st & 3] = *(const float4*)(xrow + (st + 4) * 32 + 4);
        }
        acc = __builtin_amdgcn_mfma_f32_16x16x32_bf16(pack8(x0, x1),
                                                      cf_s[st][lane], acc,
                                                      0, 0, 0);
      }
    } else {
#pragma unroll
      for (int st = 0; st < 16; ++st) {
        float4 x0 = pb0[st & 3], x1 = pb1[st & 3];
        if (st < 12) {
          pb0[st & 3] = *(const float4*)(xrow + (st + 4) * 32);
          pb1[st & 3] = *(const float4*)(xrow + (st + 4) * 32 + 4);
        }
        x2p += dot4(x0, x0) + dot4(x1, x1);
        acc = __builtin_amdgcn_mfma_f32_16x16x32_bf16(pack8(x0, x1),
                                                      cf_s[st][lane], acc,
                                                      0, 0, 0);
      }
      x2p += __shfl_xor(x2p, 16, 64);
      x2p += __shfl_xor(x2p, 32, 64);  // x2 for token tw+n (all lanes)
    }

    const float c2 = c2_s[n];

    // logits: lane holds splat n, token rows (g*4+r)  [R5-verified layout]
    float lg[4];
#pragma unroll
    for (int r = 0; r < 4; ++r) {
      float t = 2.f * acc[r] - c2;
      if (!uni) t -= __shfl(x2p, (lane & 48) | ((g << 2) + r), 64);
      lg[r] = t * inv2;
    }

    // softmax across splats (16-lane groups), 4 tokens per lane (R5-verified)
    float mx[4] = {lg[0], lg[1], lg[2], lg[3]};
#pragma unroll
    for (int dlt = 1; dlt < 16; dlt <<= 1)
#pragma unroll
      for (int r = 0; r < 4; ++r) mx[r] = fmaxf(mx[r], __shfl_xor(mx[r], dlt, 64));
    float ev[4], sm[4];
#pragma unroll
    for (int r = 0; r < 4; ++r) { ev[r] = __expf(lg[r] - mx[r]); sm[r] = ev[r]; }
#pragma unroll
    for (int dlt = 1; dlt < 16; dlt <<= 1)
#pragma unroll
      for (int r = 0; r < 4; ++r) sm[r] += __shfl_xor(sm[r], dlt, 64);

    float* ar = attn + ((size_t)b * T_ + tw) * S_;
#pragma unroll
    for (int r = 0; r < 4; ++r) {
      float av = ev[r] / sm[r];
      int trow = (g << 2) + r;
      ar[trow * S_ + n] = av;
      a_s[(w << 4) + trow][n] = av;
    }
  }

  __syncthreads();

  // ---- Phase B (exact R0/R5/R8, proven) ----
  {
    const int d = tid;  // owns cols d and d+256
    float2 acc[S_];
#pragma unroll
    for (int si = 0; si < S_; ++si) acc[si] = make_float2(0.f, 0.f);

    const float* xb = x + ((size_t)b * T_ + t0) * D_;

#pragma unroll 8
    for (int t = 0; t < CHUNK; ++t) {
      float xv0 = xb[(size_t)t * D_ + d];
      float xv1 = xb[(size_t)t * D_ + d + 256];
      const float4* ap = (const float4*)a_s[t];  // LDS broadcast
      float4 q0 = ap[0], q1 = ap[1], q2 = ap[2], q3 = ap[3];
      float av[S_] = {q0.x, q0.y, q0.z, q0.w, q1.x, q1.y, q1.z, q1.w,
                      q2.x, q2.y, q2.z, q2.w, q3.x, q3.y, q3.z, q3.w};
#pragma unroll
      for (int si = 0; si < S_; ++si) {
        acc[si].x += av[si] * xv0;
        acc[si].y += av[si] * xv1;
      }
    }

    float* tb = ts + (size_t)b * S_ * D_;
#pragma unroll
    for (int si = 0; si < S_; ++si) {
      atomicAdd(tb + si * D_ + d, acc[si].x);
      atomicAdd(tb + si * D_ + d + 256, acc[si].y);
    }
  }
}

// ---------------------------------------------------------------------------
// Kernel 2 (x2): out[r,e] = sum_k in[r,k] * W[e,k]   (r = 0..63 = b*S+s)
// Split-K=4 reduced in LDS (deterministic). 512 blocks x 256 threads.
// ---------------------------------------------------------------------------
__global__ __launch_bounds__(256) void proj_k(const float* __restrict__ in,
                                              const float* __restrict__ W,
                                              float* __restrict__ out) {
  __shared__ float red[4][64];
  const int r = blockIdx.x >> 3;
  const int eb = blockIdx.x & 7;
  const int el = threadIdx.x & 63;
  const int kc = threadIdx.x >> 6;
  const int e = (eb << 6) + el;

  const float4* w4 = (const float4*)(W + (size_t)e * D_ + kc * 128);
  const float4* i4 = (const float4*)(in + (size_t)r * D_ + kc * 128);
  float acc = 0.f;
#pragma unroll
  for (int k = 0; k < 32; ++k) acc += dot4(w4[k], i4[k]);

  red[kc][el] = acc;
  __syncthreads();
  if (kc == 0)
    out[(size_t)r * D_ + e] = red[0][el] + red[1][el] + red[2][el] + red[3][el];
}

// ---------------------------------------------------------------------------
// Kernel 3 (R10 MFMA rewrite): out[64tok x 512] = attn[64x16] @ ss_o[16x512]
// per block; K=16 GEMM on the R5-VERIFIED mfma_f32_16x16x32_bf16 with the
// k>=16 half zeroed (A-frags of lane-groups g>=2 are 0 -> B there is
// don't-care; identical fragment + D layouts to R5, no new layout risk).
// ss_o (128 KB, L2-hot) staged once/block into LDS bf16 frags [et][n][k].
// Kills the old 64-iter dependent-load chain; kernel = 64 MB store stream.
// 512 blocks x 256 threads; wave w owns tokens t0+16w..+15.
// ---------------------------------------------------------------------------
__global__ __launch_bounds__(256) void out_k(const float* __restrict__ attn,
                                             const float* __restrict__ ss_o,
                                             float* __restrict__ out) {
  __shared__ __align__(16) __hip_bfloat16 bs[32][16][16];  // [et][n][k] 16 KB
  const int tid = threadIdx.x;
  const int lane = tid & 63;
  const int w = tid >> 6;
  const int g = lane >> 4;   // k-group 0..3 (g>=2 carries zeros, K=16)
  const int n = lane & 15;
  const int b = blockIdx.x >> 7;
  const int t0 = (blockIdx.x & 127) * 64;
  const int tw = t0 + (w << 4);

  // ---- stage ss_o -> LDS bf16 fragments (thread owns cols tid, tid+256) ----
  {
    const float* sb = ss_o + (size_t)b * S_ * D_;
    const int e0 = tid, e1 = tid + 256;
#pragma unroll
    for (int s = 0; s < S_; ++s) {
      bs[e0 >> 4][e0 & 15][s] = __float2bfloat16(sb[s * D_ + e0]);
      bs[e1 >> 4][e1 & 15][s] = __float2bfloat16(sb[s * D_ + e1]);
    }
  }
  __syncthreads();

  // ---- A-fragment: attn rows tw+m (m=n), k=g*8..+7 real for g<2 ----
  bf16x8 af = {0, 0, 0, 0, 0, 0, 0, 0};
  {
    const float* arow = attn + ((size_t)b * T_ + tw + n) * S_ + ((g & 1) << 3);
    float4 a0 = *(const float4*)(arow);
    float4 a1 = *(const float4*)(arow + 4);
    bf16x8 full = pack8(a0, a1);
    if (g < 2) af = full;  // g>=2: zero (k>=16 half of the MFMA is unused)
  }

  // ---- 32 e-tiles: ds_read_b128 B-frag, one MFMA, 4 stores ----
  float* ob = out + ((size_t)b * T_ + tw) * D_;
#pragma unroll 4
  for (int et = 0; et < 32; ++et) {
    // B-frag: k=g*8..+7 at col n; g>=2 reads g&1 (don't-care, A is zero there)
    bf16x8 bfr = *(const bf16x8*)&bs[et][n][(g & 1) << 3];
    f32x4 z = {0.f, 0.f, 0.f, 0.f};
    f32x4 d = __builtin_amdgcn_mfma_f32_16x16x32_bf16(af, bfr, z, 0, 0, 0);
    // D: col n -> out col et*16+n; rows g*4+r  [R5-verified layout]
    float* oc = ob + et * 16 + n;
#pragma unroll
    for (int r = 0; r < 4; ++r) oc[(size_t)((g << 2) + r) * D_] = d[r];
  }
}

// ---------------------------------------------------------------------------
extern "C" void kernel_launch(void* const* d_in, const int* in_sizes, int n_in,
                              void* d_out, int out_size, void* d_ws, size_t ws_size,
                              hipStream_t stream) {
  const float* x          = (const float*)d_in[0];  // [B,T,D]
  const float* centers    = (const float*)d_in[1];  // [S,D]
  const float* log_scales = (const float*)d_in[2];  // [S]
  const float* Wv         = (const float*)d_in[3];  // [D,D]
  const float* Wo         = (const float*)d_in[4];  // [D,D]
  float* out = (float*)d_out;                       // [B,T,D]

  // workspace layout (floats): attn | ts | tmp | ss_o
  float* attn = (float*)d_ws;                        // B*T*S   = 2 MB
  float* ts   = attn + (size_t)B_ * T_ * S_;         // B*S*D   = 128 KB
  float* tmp  = ts + (size_t)B_ * S_ * D_;           // B*S*D   = 128 KB
  float* ss_o = tmp + (size_t)B_ * S_ * D_;          // B*S*D   = 128 KB

  // zero only the atomic target (tiny, L2-resident fill)
  hipMemsetAsync(ts, 0, (size_t)B_ * S_ * D_ * sizeof(float), stream);

  attn_ts_k<<<B_ * (T_ / CHUNK), 256, 0, stream>>>(x, centers, log_scales, attn, ts);
  proj_k<<<512, 256, 0, stream>>>(ts, Wv, tmp);    // tmp = ts @ Wv^T
  proj_k<<<512, 256, 0, stream>>>(tmp, Wo, ss_o);  // ss_o = tmp @ Wo^T
  out_k<<<512, 256, 0, stream>>>(attn, ss_o, out);
}